// Round 3
// baseline (28049.042 us; speedup 1.0000x reference)
//
#include <hip/hip_runtime.h>
#include <cstdint>

#define S_LEN 8192
#define BATCH 4096

// 256 blocks x 256 threads (4 waves). Each block owns 16 batch elements.
// Wave w computes output hidden units j in [32w, 32w+32) via MFMA
// D[j'][elem] = sum_i W2^T[j'][i] * h1[i][elem], f16 operands, f32 accum.
// W2^T lives in registers as A-fragments (loaded once). Layer-1 h1 is
// computed per-lane directly in B-fragment layout (no LDS, no shuffles).
// Only cross-wave traffic: 4 layer-3 partials per element per eval through
// a 512 B double-buffered LDS buffer + one barrier per eval.

typedef _Float16 f16x8 __attribute__((ext_vector_type(8)));
typedef float f32x4 __attribute__((ext_vector_type(4)));

__device__ __forceinline__ float fast_tanh(float x) {
  // tanh(x) = 1 - 2/(exp(2x)+1); exp(2x)=exp2(2*log2e*x). Saturates cleanly.
  float e = __builtin_amdgcn_exp2f(x * 2.8853900817779268f);
  return __builtin_fmaf(-2.0f, __builtin_amdgcn_rcpf(e + 1.0f), 1.0f);
}

struct LaneCtx {
  f16x8 af[2][4];     // W2^T A-frags: [jb2][kb]
  f32x4 b2f[2];       // C-init (bias2) per jb2
  float W3f[2][4];    // W3 at this lane's D slots
  float W10s[4][8];   // W1[0][i] at this lane's B k-slots [kb][r]
  float W11s[4][8];   // W1[1][i]
  float b1s[4][8];    // b1[i]
  float b3s;
};

template <int BUF>
__device__ __forceinline__ float eval_stage(float y, const float cv[4][8],
                                            const LaneCtx& C, float* pbuf,
                                            int l, int e, int w) {
  // ---- layer 1: h1 in B-fragment layout (k = q*8+r per kb) ----
  f16x8 hf[4];
#pragma unroll
  for (int kb = 0; kb < 4; ++kb) {
#pragma unroll
    for (int r = 0; r < 8; ++r) {
      float pre = __builtin_fmaf(y, C.W11s[kb][r], cv[kb][r]);
      hf[kb][r] = (_Float16)fast_tanh(pre);  // RNE
    }
  }

  // ---- layer 2: 8 MFMAs, accumulate over kb ----
  f32x4 acc0 = C.b2f[0];
  f32x4 acc1 = C.b2f[1];
#pragma unroll
  for (int kb = 0; kb < 4; ++kb) {
    acc0 = __builtin_amdgcn_mfma_f32_16x16x32_f16(C.af[0][kb], hf[kb], acc0, 0, 0, 0);
    acc1 = __builtin_amdgcn_mfma_f32_16x16x32_f16(C.af[1][kb], hf[kb], acc1, 0, 0, 0);
  }

  // ---- layer 3 partial: tanh + dot with W3 slice ----
  float p = 0.0f;
#pragma unroll
  for (int r = 0; r < 4; ++r) p = __builtin_fmaf(fast_tanh(acc0[r]), C.W3f[0][r], p);
#pragma unroll
  for (int r = 0; r < 4; ++r) p = __builtin_fmaf(fast_tanh(acc1[r]), C.W3f[1][r], p);

  // reduce across the 4 k-groups (lanes differing in bits 4,5)
  p += __shfl_xor(p, 16, 64);
  p += __shfl_xor(p, 32, 64);

  // ---- cross-wave exchange: pbuf[BUF][elem][wave] ----
  if (l < 16) pbuf[BUF * 64 + l * 4 + w] = p;
  __syncthreads();
  const f32x4 pp = *reinterpret_cast<const f32x4*>(&pbuf[BUF * 64 + e * 4]);
  return pp[0] + pp[1] + pp[2] + pp[3] + C.b3s;
}

__global__ __launch_bounds__(256, 1) void rk4_mfma_kernel(
    const float* __restrict__ x, const float* __restrict__ W1,
    const float* __restrict__ b1, const float* __restrict__ W2,
    const float* __restrict__ b2, const float* __restrict__ W3,
    const float* __restrict__ b3, float* __restrict__ out) {
  __shared__ float pbuf[2 * 16 * 4];

  const int t = threadIdx.x;
  const int w = t >> 6;        // wave 0..3
  const int l = t & 63;        // lane
  const int e = l & 15;        // element column (MFMA n / A m)
  const int q = l >> 4;        // k-group 0..3
  const int base = blockIdx.x * 16;

  LaneCtx C;

  // ---- one-time weight staging into registers ----
#pragma unroll
  for (int jb2 = 0; jb2 < 2; ++jb2) {
    const int jA = w * 32 + jb2 * 16 + e;  // A-operand row (m = l&15)
#pragma unroll
    for (int kb = 0; kb < 4; ++kb) {
#pragma unroll
      for (int r = 0; r < 8; ++r) {
        const int i = kb * 32 + q * 8 + r;
        C.af[jb2][kb][r] = (_Float16)W2[i * 128 + jA];  // W2^T[j][i]
      }
    }
    // D/C-layout slots: row = q*4 + r
#pragma unroll
    for (int r = 0; r < 4; ++r) {
      const int jD = w * 32 + jb2 * 16 + q * 4 + r;
      C.b2f[jb2][r] = b2[jD];
      C.W3f[jb2][r] = W3[jD];
    }
  }
#pragma unroll
  for (int kb = 0; kb < 4; ++kb) {
#pragma unroll
    for (int r = 0; r < 8; ++r) {
      const int i = kb * 32 + q * 8 + r;
      C.W10s[kb][r] = W1[i];        // W1[0][i]
      C.W11s[kb][r] = W1[128 + i];  // W1[1][i]
      C.b1s[kb][r] = b1[i];
    }
  }
  C.b3s = b3[0];

  float y = 0.0f;
  float v = x[base + e];
  float cv[4][8];

  for (int s = 0; s < S_LEN; ++s) {
    const int nxt = (s + 1 < S_LEN) ? (s + 1) : s;
    const float vn = x[(size_t)nxt * BATCH + base + e];

    // v-dependent half of layer 1, shared by all 4 RK stages
#pragma unroll
    for (int kb = 0; kb < 4; ++kb)
#pragma unroll
      for (int r = 0; r < 8; ++r)
        cv[kb][r] = __builtin_fmaf(v, C.W10s[kb][r], C.b1s[kb][r]);

    const float k1 = eval_stage<0>(y, cv, C, pbuf, l, e, w);
    const float k2 = eval_stage<1>(__builtin_fmaf(0.5f, k1, y), cv, C, pbuf, l, e, w);
    const float k3 = eval_stage<0>(__builtin_fmaf(0.5f, k2, y), cv, C, pbuf, l, e, w);
    const float k4 = eval_stage<1>(y + k3, cv, C, pbuf, l, e, w);

    y = __builtin_fmaf(k1 + 2.0f * (k2 + k3) + k4, 0.16666666666666666f, y);

    if (t < 16) out[(size_t)s * BATCH + base + t] = y;
    v = vn;
  }
}

extern "C" void kernel_launch(void* const* d_in, const int* in_sizes, int n_in,
                              void* d_out, int out_size, void* d_ws, size_t ws_size,
                              hipStream_t stream) {
  const float* x  = (const float*)d_in[0];
  const float* W1 = (const float*)d_in[1];
  const float* b1 = (const float*)d_in[2];
  const float* W2 = (const float*)d_in[3];
  const float* b2 = (const float*)d_in[4];
  const float* W3 = (const float*)d_in[5];
  const float* b3 = (const float*)d_in[6];
  float* out = (float*)d_out;

  hipLaunchKernelGGL(rk4_mfma_kernel, dim3(256), dim3(256), 0, stream,
                     x, W1, b1, W2, b2, W3, b3, out);
}

// Round 6
// 18433.722 us; speedup vs baseline: 1.5216x; 1.5216x over previous
//
#include <hip/hip_runtime.h>
#include <cstdint>

#define S_LEN 8192
#define BATCH 4096

// 256 blocks x 512 threads (8 waves). Block owns 16 batch elements.
// Wave w owns output hidden units j in [16w, 16w+16): 4 MFMAs (16x16x32) per eval.
// Layer-1 h1 (2048 values = 128 i x 16 e) is computed ONCE per block-eval,
// cooperatively: each lane produces 4 values (one half of a 16B B-frag slot),
// written to LDS at t*8 (dense ds_write_b64), then every wave reads the shared
// B-fragments with 4x ds_read_b128. Layer-3 partials (8 waves) exchanged via
// a 512 B pbuf. Two barriers per eval. fp32 state, f16 MFMA operands (RNE).

typedef _Float16 f16x8 __attribute__((ext_vector_type(8)));
typedef _Float16 f16x4 __attribute__((ext_vector_type(4)));
typedef float f32x4 __attribute__((ext_vector_type(4)));

__device__ __forceinline__ float fast_tanh(float x) {
  // tanh(x) = 1 - 2/(exp(2x)+1); exp2 saturates cleanly to +/-1 for large |x|.
  float e = __builtin_amdgcn_exp2f(x * 2.8853900817779268f);
  return __builtin_fmaf(-2.0f, __builtin_amdgcn_rcpf(e + 1.0f), 1.0f);
}

struct Ctx {
  f16x8 af[4];                    // W2^T A-frags, one per 32-wide k-block
  f32x4 b2f;                      // C-init (bias2) at this lane's D slots
  float W3f[4];                   // W3 at this lane's D slots
  float W10p[4], W11p[4], b1p[4]; // layer-1 weights for the 4 produced h1 values
  float b3s;
};

__device__ __forceinline__ float eval8(float y, const float cv[4], const Ctx& C,
                                       unsigned char* h1b, float* pbuf,
                                       int t, int l, int w, int ep) {
  // ---- produce this lane's 4 h1 values (B-frag layout half-slot) ----
  f16x4 hv;
#pragma unroll
  for (int rr = 0; rr < 4; ++rr) {
    float pre = __builtin_fmaf(y, C.W11p[rr], cv[rr]);
    hv[rr] = (_Float16)fast_tanh(pre);  // RNE
  }
  *reinterpret_cast<f16x4*>(h1b + t * 8) = hv;  // addr t*8 == slot*16 + half*8
  __syncthreads();

  // ---- read shared B-fragments ----
  f16x8 hf[4];
#pragma unroll
  for (int kb = 0; kb < 4; ++kb)
    hf[kb] = *reinterpret_cast<const f16x8*>(h1b + (kb * 64 + l) * 16);

  // ---- layer 2: 4 MFMAs over k-blocks ----
  f32x4 acc = C.b2f;
#pragma unroll
  for (int kb = 0; kb < 4; ++kb)
    acc = __builtin_amdgcn_mfma_f32_16x16x32_f16(C.af[kb], hf[kb], acc, 0, 0, 0);

  // ---- layer 3 partial + intra-wave reduce over k-groups ----
  float p = 0.0f;
#pragma unroll
  for (int r = 0; r < 4; ++r) p = __builtin_fmaf(fast_tanh(acc[r]), C.W3f[r], p);
  p += __shfl_xor(p, 16, 64);
  p += __shfl_xor(p, 32, 64);

  // ---- cross-wave exchange: pbuf[eD][w], eD = l for l<16 ----
  if (l < 16) pbuf[l * 8 + w] = p;
  __syncthreads();
  const f32x4 pa = *reinterpret_cast<const f32x4*>(&pbuf[ep * 8]);
  const f32x4 pb = *reinterpret_cast<const f32x4*>(&pbuf[ep * 8 + 4]);
  return (((pa[0] + pa[1]) + (pa[2] + pa[3])) +
          ((pb[0] + pb[1]) + (pb[2] + pb[3]))) + C.b3s;
}

__global__ __launch_bounds__(512, 2) void rk4_mfma8_kernel(
    const float* __restrict__ x, const float* __restrict__ W1,
    const float* __restrict__ b1, const float* __restrict__ W2,
    const float* __restrict__ b2, const float* __restrict__ W3,
    const float* __restrict__ b3, float* __restrict__ out) {
  __shared__ __align__(16) unsigned char h1b[4096];  // 256 slots x 16B
  __shared__ float pbuf[16 * 8];

  const int t = threadIdx.x;
  const int w = t >> 6;          // wave 0..7
  const int l = t & 63;          // lane
  const int q = (l >> 4) & 3;    // k-group within wave (A/D row group)
  const int eD = l & 15;         // A m-index / D column
  const int slot = t >> 1;       // h1 production slot 0..255
  const int half = t & 1;        // which 8B half of the 16B slot
  const int kbp = slot >> 6;     // produced k-block
  const int qp = (slot >> 4) & 3;
  const int ep = slot & 15;      // element whose (v,y) this lane tracks
  const int base = blockIdx.x * 16;

  Ctx C;
  const int jbase = w * 16;
#pragma unroll
  for (int kb = 0; kb < 4; ++kb)
#pragma unroll
    for (int r = 0; r < 8; ++r) {
      const int k = kb * 32 + q * 8 + r;
      C.af[kb][r] = (_Float16)W2[k * 128 + jbase + eD];  // W2^T[j][k]
    }
#pragma unroll
  for (int r = 0; r < 4; ++r) {
    const int j = jbase + q * 4 + r;  // D row = q*4+r
    C.b2f[r] = b2[j];
    C.W3f[r] = W3[j];
  }
#pragma unroll
  for (int rr = 0; rr < 4; ++rr) {
    const int k = kbp * 32 + qp * 8 + half * 4 + rr;
    C.W10p[rr] = W1[k];
    C.W11p[rr] = W1[128 + k];
    C.b1p[rr] = b1[k];
  }
  C.b3s = b3[0];

  float y = 0.0f;
  float v = x[base + ep];
  float cv[4];

  for (int s = 0; s < S_LEN; ++s) {
    const int nxt = (s + 1 < S_LEN) ? (s + 1) : s;
    const float vn = x[(size_t)nxt * BATCH + base + ep];

    // v-dependent half of layer 1, shared by all 4 RK stages
#pragma unroll
    for (int rr = 0; rr < 4; ++rr)
      cv[rr] = __builtin_fmaf(v, C.W10p[rr], C.b1p[rr]);

    const float k1 = eval8(y, cv, C, h1b, pbuf, t, l, w, ep);
    const float k2 = eval8(__builtin_fmaf(0.5f, k1, y), cv, C, h1b, pbuf, t, l, w, ep);
    const float k3 = eval8(__builtin_fmaf(0.5f, k2, y), cv, C, h1b, pbuf, t, l, w, ep);
    const float k4 = eval8(y + k3, cv, C, h1b, pbuf, t, l, w, ep);

    y = __builtin_fmaf(k1 + 2.0f * (k2 + k3) + k4, 0.16666666666666666f, y);

    // writers: wave 0, even lanes -> ep = t>>1 covers 0..15 exactly once
    if (t < 32 && half == 0) out[(size_t)s * BATCH + base + ep] = y;
    v = vn;
  }
}

extern "C" void kernel_launch(void* const* d_in, const int* in_sizes, int n_in,
                              void* d_out, int out_size, void* d_ws, size_t ws_size,
                              hipStream_t stream) {
  const float* x  = (const float*)d_in[0];
  const float* W1 = (const float*)d_in[1];
  const float* b1 = (const float*)d_in[2];
  const float* W2 = (const float*)d_in[3];
  const float* b2 = (const float*)d_in[4];
  const float* W3 = (const float*)d_in[5];
  const float* b3 = (const float*)d_in[6];
  float* out = (float*)d_out;

  hipLaunchKernelGGL(rk4_mfma8_kernel, dim3(256), dim3(512), 0, stream,
                     x, W1, b1, W2, b2, W3, b3, out);
}